// Round 15
// baseline (327.195 us; speedup 1.0000x reference)
//
#include <hip/hip_runtime.h>
#include <hip/hip_bf16.h>
#include <stdint.h>

// ---------------------------------------------------------------------------
// LoRALinear: y = x @ (W + B@A)^T + (b + lora_bias)
// M=8192, N=4096, K=4096.
// R15: 1-barrier-per-K-tile interleaved schedule (AITER pattern in plain HIP):
//  - stage ALL of t+1 into par^1 at tile top (regions free since t-1's end
//    barrier -> no intra-tile publication barrier needed at all)
//  - counted lgkm: issue b01,a03,b23; lgkm(4)->Q00; lgkm(0)->Q01; issue a47
//    (WAR reuse of a03 regs); lgkm(0)->Q10+Q11 (32-MFMA burst)
//  - vmcnt(0) at tile end is FREE (loads aged a full tile; B L2-resident)
//  - sched_barrier(0) after every counted asm lgkm (rule #18)
// R4/R11 lesson: ~250 regs/wave cap -> acc[8][4] + 64 operand regs only.
// R13 lesson: 8-barrier lockstep caps at 46% MfmaUtil; phase permutations
//             (R6/R9/R14) are noise. The binder is per-phase LGKM0 serialization.
// ---------------------------------------------------------------------------

#define M_DIM 8192
#define N_DIM 4096
#define K_DIM 4096
#define NT    (K_DIM / 64)   // 64 K-tiles

typedef __attribute__((ext_vector_type(8))) short bf16x8;
typedef __attribute__((ext_vector_type(4))) float f32x4;

#define BARRIER() __builtin_amdgcn_s_barrier()
#define WAITV0() asm volatile("s_waitcnt vmcnt(0)" ::: "memory")
// counted lgkm + scheduling fence (rule #18: pin MFMAs below the wait)
#define LGKMW(n) do { asm volatile("s_waitcnt lgkmcnt(" #n ")" ::: "memory"); \
                      __builtin_amdgcn_sched_barrier(0); } while (0)

static __device__ __forceinline__ unsigned short f2bf(float f) {
    unsigned int u = __builtin_bit_cast(unsigned int, f);
    unsigned int r = (u + 0x7fffu + ((u >> 16) & 1u)) >> 16;
    return (unsigned short)r;
}

// --- conv_x: bf16(x) --------------------------------------------------------
__global__ __launch_bounds__(256) void conv_x_kernel(
    const float* __restrict__ x, unsigned short* __restrict__ xb) {
    size_t i = ((size_t)blockIdx.x * 256 + threadIdx.x) * 8;
    float4 a = *(const float4*)(x + i);
    float4 c = *(const float4*)(x + i + 4);
    union { unsigned short us[8]; uint4 v; } u;
    u.us[0] = f2bf(a.x); u.us[1] = f2bf(a.y); u.us[2] = f2bf(a.z); u.us[3] = f2bf(a.w);
    u.us[4] = f2bf(c.x); u.us[5] = f2bf(c.y); u.us[6] = f2bf(c.z); u.us[7] = f2bf(c.w);
    *(uint4*)(xb + i) = u.v;
}

// --- conv_w: bf16(W + B@A). 4 rows/block, lA read once per block. ----------
__global__ __launch_bounds__(512) void conv_w_kernel(
    const float* __restrict__ W, const float* __restrict__ lA,
    const float* __restrict__ lB, unsigned short* __restrict__ Wb) {
    const int nb = blockIdx.x * 4;        // 1024 blocks
    const int k0 = threadIdx.x * 8;       // 512 thr * 8 = 4096

    float acc[4][8];
#pragma unroll
    for (int r = 0; r < 4; ++r) {
        const float4* w4 = (const float4*)(W + (size_t)(nb + r) * K_DIM + k0);
        float4 v0 = w4[0], v1 = w4[1];
        acc[r][0] = v0.x; acc[r][1] = v0.y; acc[r][2] = v0.z; acc[r][3] = v0.w;
        acc[r][4] = v1.x; acc[r][5] = v1.y; acc[r][6] = v1.z; acc[r][7] = v1.w;
    }
    float brs[4][16];
#pragma unroll
    for (int r = 0; r < 4; ++r)
#pragma unroll
        for (int t = 0; t < 16; ++t) brs[r][t] = lB[(size_t)(nb + r) * 16 + t];

#pragma unroll
    for (int t = 0; t < 16; ++t) {
        const float4* a4 = (const float4*)(lA + (size_t)t * K_DIM + k0);
        float4 v0 = a4[0], v1 = a4[1];
        float av[8] = {v0.x, v0.y, v0.z, v0.w, v1.x, v1.y, v1.z, v1.w};
#pragma unroll
        for (int r = 0; r < 4; ++r)
#pragma unroll
            for (int j = 0; j < 8; ++j) acc[r][j] += brs[r][t] * av[j];
    }
#pragma unroll
    for (int r = 0; r < 4; ++r) {
        union { unsigned short us[8]; uint4 v; } u;
#pragma unroll
        for (int j = 0; j < 8; ++j) u.us[j] = f2bf(acc[r][j]);
        *(uint4*)(Wb + (size_t)(nb + r) * K_DIM + k0) = u.v;
    }
}

// --- gemm: 256x256 tile, BK=64, 8 waves, 1-barrier/KT interleaved loop ------
__global__ __launch_bounds__(512, 2) void gemm_kernel(
    const unsigned short* __restrict__ A,   // [8192][4096] bf16
    const unsigned short* __restrict__ B,   // [4096][4096] bf16 (W')
    const float* __restrict__ bvec, const float* __restrict__ lbvec,
    float* __restrict__ C) {
    const int tid = threadIdx.x;
    const int lane = tid & 63;
    const int wid = tid >> 6;        // 0..7
    const int wr = wid >> 2;         // 0..1  M-half (128 rows)
    const int wc = wid & 3;          // 0..3  N-quarter (64 cols)

    // XCD-column-resident mapping (R7)
    const int bid = blockIdx.x;
    const int ntile = (bid & 7) * 2 + ((bid >> 3) & 1);  // 0..15
    const int mtile = bid >> 4;                          // 0..31
    const int m0 = mtile * 256, n0 = ntile * 256;

    __shared__ __align__(16) unsigned short ldsA[2 * 2 * 128 * 64];  // 64 KiB
    __shared__ __align__(16) unsigned short ldsB[2 * 2 * 128 * 64];  // 64 KiB

    // --- staging: linear LDS dest, inverse-swizzled global src (T2) ---
    const int lr8 = lane >> 3;             // 0..7
    const int cch = (lane & 7) ^ lr8;      // swizzled 16B-chunk index
    const unsigned short* aSb = A + (size_t)(m0 + lr8) * K_DIM + cch * 8;
    const unsigned short* bSb = B + (size_t)(n0 + lr8) * K_DIM + cch * 8;

    auto stageA = [&](int par_, int h, int kt) {   // one half-tile = 2 loads
#pragma unroll
        for (int s = 0; s < 2; ++s) {
            const int j = wid * 2 + s;
            const unsigned short* g = aSb + (size_t)(h * 128 + j * 8) * K_DIM + kt * 64;
            __builtin_amdgcn_global_load_lds(
                (const __attribute__((address_space(1))) void*)g,
                (__attribute__((address_space(3))) void*)(ldsA + (par_ * 2 + h) * 8192 + j * 512),
                16, 0, 0);
        }
    };
    auto stageB = [&](int par_, int h, int kt) {
#pragma unroll
        for (int s = 0; s < 2; ++s) {
            const int j = wid * 2 + s;
            const unsigned short* g = bSb + (size_t)(h * 128 + j * 8) * K_DIM + kt * 64;
            __builtin_amdgcn_global_load_lds(
                (const __attribute__((address_space(1))) void*)g,
                (__attribute__((address_space(3))) void*)(ldsB + (par_ * 2 + h) * 8192 + j * 512),
                16, 0, 0);
        }
    };

    // --- read side (T2 swizzle) ---
    const int rowByte = (lane & 15) * 128;
    const int swz = (lane & 7) << 4;
    const int kc0 = (0 * 64 + (lane >> 4) * 16) ^ swz;
    const int kc1 = (1 * 64 + (lane >> 4) * 16) ^ swz;
    const int baseBoff = (wc & 1) * 4096;

    auto readA = [&](int par_, int mf, int kk) -> bf16x8 {
        const char* p = (const char*)(ldsA + (par_ * 2 + wr) * 8192 + mf * 1024) +
                        rowByte + (kk ? kc1 : kc0);
        return *(const bf16x8*)p;
    };
    auto readB = [&](int par_, int nf, int kk) -> bf16x8 {
        const char* p = (const char*)(ldsB + (par_ * 2 + (wc >> 1)) * 8192 + baseBoff + nf * 1024) +
                        rowByte + (kk ? kc1 : kc0);
        return *(const bf16x8*)p;
    };

    f32x4 acc[8][4] = {};
    bf16x8 a[4][2], b[4][2];

    auto mfmaQ = [&](int qm, int qn) {   // 16 MFMA: 4 mf x 2 nf x 2 kk
#pragma unroll
        for (int i = 0; i < 4; ++i)
#pragma unroll
            for (int jn = 0; jn < 2; ++jn)
#pragma unroll
                for (int kk = 0; kk < 2; ++kk)
                    acc[qm * 4 + i][qn * 2 + jn] = __builtin_amdgcn_mfma_f32_16x16x32_bf16(
                        a[i][kk], b[qn * 2 + jn][kk], acc[qm * 4 + i][qn * 2 + jn], 0, 0, 0);
    };

    // --- prologue: stage t0; free drain; publish ---
    stageA(0, 0, 0); stageA(0, 1, 0); stageB(0, 0, 0); stageB(0, 1, 0);
    WAITV0();
    BARRIER();

    // Per K-tile (ONE barrier):
    //  stage t+1 -> par^1 ; reads b01,a03,b23 ; lgkm(4) Q00 ; lgkm(0) Q01 ;
    //  reads a47 (reuse regs) ; lgkm(0) Q10+Q11 ; vmcnt(0) ; BAR.
#define KTILE(kt, par)                                                          \
    {                                                                           \
        if ((kt) + 1 < NT) {                                                    \
            stageA((par) ^ 1, 0, (kt) + 1); stageA((par) ^ 1, 1, (kt) + 1);     \
            stageB((par) ^ 1, 0, (kt) + 1); stageB((par) ^ 1, 1, (kt) + 1);     \
        }                                                                       \
        _Pragma("unroll") for (int nf = 0; nf < 2; ++nf)                        \
            _Pragma("unroll") for (int kk = 0; kk < 2; ++kk)                    \
                b[nf][kk] = readB(par, nf, kk);                                  \
        _Pragma("unroll") for (int i = 0; i < 4; ++i)                           \
            _Pragma("unroll") for (int kk = 0; kk < 2; ++kk)                    \
                a[i][kk] = readA(par, i, kk);                                    \
        _Pragma("unroll") for (int nf = 2; nf < 4; ++nf)                        \
            _Pragma("unroll") for (int kk = 0; kk < 2; ++kk)                    \
                b[nf][kk] = readB(par, nf, kk);                                  \
        LGKMW(4);                                                               \
        __builtin_amdgcn_s_setprio(1); mfmaQ(0, 0); __builtin_amdgcn_s_setprio(0); \
        LGKMW(0);                                                               \
        __builtin_amdgcn_s_setprio(1); mfmaQ(0, 1); __builtin_amdgcn_s_setprio(0); \
        _Pragma("unroll") for (int i = 0; i < 4; ++i)                           \
            _Pragma("unroll") for (int kk = 0; kk < 2; ++kk)                    \
                a[i][kk] = readA(par, 4 + i, kk);                                \
        LGKMW(0);                                                               \
        __builtin_amdgcn_s_setprio(1); mfmaQ(1, 0); mfmaQ(1, 1);                \
        __builtin_amdgcn_s_setprio(0);                                          \
        WAITV0();                                                               \
        BARRIER();                                                              \
    }

#pragma unroll 1
    for (int kt = 0; kt < NT; kt += 2) {
        KTILE(kt, 0);
        KTILE(kt + 1, 1);
    }
#undef KTILE

    // --- epilogue: C = acc + (b + lora_bias); NT stores ---
#pragma unroll
    for (int nf = 0; nf < 4; ++nf) {
        const int gc = n0 + wc * 64 + nf * 16 + (lane & 15);
        const float bv = bvec[gc] + lbvec[gc];
#pragma unroll
        for (int mf = 0; mf < 8; ++mf) {
            const int gr0 = m0 + wr * 128 + mf * 16 + (lane >> 4) * 4;
            f32x4 v = acc[mf][nf];
#pragma unroll
            for (int j = 0; j < 4; ++j)
                __builtin_nontemporal_store(v[j] + bv, &C[(size_t)(gr0 + j) * N_DIM + gc]);
        }
    }
}

// --- Fallback: naive fp32 (only if ws too small) ----------------------------
__global__ __launch_bounds__(256) void naive_kernel(
    const float* __restrict__ x, const float* __restrict__ W,
    const float* __restrict__ b, const float* __restrict__ lA,
    const float* __restrict__ lB, const float* __restrict__ lb,
    float* __restrict__ out) {
    __shared__ float xs[K_DIM];
    __shared__ float ts[16];
    const int m = blockIdx.x;
    const int tid = threadIdx.x;
    for (int k = tid; k < K_DIM; k += 256) xs[k] = x[(size_t)m * K_DIM + k];
    if (tid < 16) ts[tid] = 0.f;
    __syncthreads();
    float part[16] = {};
    for (int k = tid * 16; k < tid * 16 + 16; ++k) {
        float xv = xs[k];
#pragma unroll
        for (int r = 0; r < 16; ++r) part[r] += xv * lA[(size_t)r * K_DIM + k];
    }
#pragma unroll
    for (int r = 0; r < 16; ++r) atomicAdd(&ts[r], part[r]);
    __syncthreads();
    const int n = blockIdx.y * 256 + tid;
    float acc = b[n] + lb[n];
#pragma unroll
    for (int r = 0; r < 16; ++r) acc += ts[r] * lB[(size_t)n * 16 + r];
    const float* wrow = W + (size_t)n * K_DIM;
    for (int k = 0; k < K_DIM; ++k) acc += xs[k] * wrow[k];
    out[(size_t)m * N_DIM + n] = acc;
}

// ---------------------------------------------------------------------------
extern "C" void kernel_launch(void* const* d_in, const int* in_sizes, int n_in,
                              void* d_out, int out_size, void* d_ws, size_t ws_size,
                              hipStream_t stream) {
    const float* x  = (const float*)d_in[0];
    const float* W  = (const float*)d_in[1];
    const float* b  = (const float*)d_in[2];
    const float* lA = (const float*)d_in[3];
    const float* lB = (const float*)d_in[4];
    const float* lb = (const float*)d_in[5];
    float* out = (float*)d_out;

    const size_t xb_bytes = (size_t)M_DIM * K_DIM * 2;  // 64 MiB
    const size_t wb_bytes = (size_t)N_DIM * K_DIM * 2;  // 32 MiB

    if (ws_size >= xb_bytes + wb_bytes) {
        unsigned short* xb = (unsigned short*)d_ws;
        unsigned short* wb = (unsigned short*)((char*)d_ws + xb_bytes);

        conv_x_kernel<<<(M_DIM * K_DIM) / (256 * 8), 256, 0, stream>>>(x, xb);
        conv_w_kernel<<<N_DIM / 4, 512, 0, stream>>>(W, lA, lB, wb);

        gemm_kernel<<<(M_DIM / 256) * (N_DIM / 256), 512, 0, stream>>>(xb, wb, b, lb, out);
    } else {
        dim3 grid(M_DIM, N_DIM / 256);
        naive_kernel<<<grid, 256, 0, stream>>>(x, W, b, lA, lB, lb, out);
    }
}

// Round 16
// 305.560 us; speedup vs baseline: 1.0708x; 1.0708x over previous
//
#include <hip/hip_runtime.h>
#include <hip/hip_bf16.h>
#include <stdint.h>

// ---------------------------------------------------------------------------
// LoRALinear: y = x @ (W + B@A)^T + (b + lora_bias)
// M=8192, N=4096, K=4096.
// R16: gemm = R13 champion (byte-identical; best of 11 schedule variants,
// 264us / 1041 TF / MfmaUtil 46 / conflicts 0). conv_x+conv_w merged into
// one launch (both BW-bound; saves launch gap, overlaps head/tail).
// Mechanism ledger (established): wall/KT = MFMA(2483) + LDS(~2300) +
// sync(~700) serial; per-wave LDS read volume already minimal; all HIP-level
// de-phasing levers falsified (R6,R9,R10,R12,R14,R15); reg-dbuf needs >256
// regs (R11); acc[8][8] spills (R4); fp8 predicted over threshold.
// ---------------------------------------------------------------------------

#define M_DIM 8192
#define N_DIM 4096
#define K_DIM 4096
#define NT    (K_DIM / 64)   // 64 K-tiles

typedef __attribute__((ext_vector_type(8))) short bf16x8;
typedef __attribute__((ext_vector_type(4))) float f32x4;

#define BARRIER() __builtin_amdgcn_s_barrier()
#define WAITV8() asm volatile("s_waitcnt vmcnt(8)" ::: "memory")
#define WAITV4() asm volatile("s_waitcnt vmcnt(4)" ::: "memory")
#define WAITV0() asm volatile("s_waitcnt vmcnt(0)" ::: "memory")
#define LGKM0()  asm volatile("s_waitcnt lgkmcnt(0)" ::: "memory")
#define LGKM8()  asm volatile("s_waitcnt lgkmcnt(8)" ::: "memory")

static __device__ __forceinline__ unsigned short f2bf(float f) {
    unsigned int u = __builtin_bit_cast(unsigned int, f);
    unsigned int r = (u + 0x7fffu + ((u >> 16) & 1u)) >> 16;
    return (unsigned short)r;
}

// --- merged pre-pass: blocks [0,8192) convert x -> bf16 (8 elems/thread);
//     blocks [8192,9216) compute bf16(W + B@A), 4 rows/block. -----------------
#define CONVX_BLOCKS 8192
__global__ __launch_bounds__(512) void conv_xw_kernel(
    const float* __restrict__ x, unsigned short* __restrict__ xb,
    const float* __restrict__ W, const float* __restrict__ lA,
    const float* __restrict__ lB, unsigned short* __restrict__ Wb) {
    const int bid = blockIdx.x;
    if (bid < CONVX_BLOCKS) {
        // ---- conv_x part: 8192 blocks x 512 thr x 8 elems = 32M ----
        size_t i = ((size_t)bid * 512 + threadIdx.x) * 8;
        float4 a = *(const float4*)(x + i);
        float4 c = *(const float4*)(x + i + 4);
        union { unsigned short us[8]; uint4 v; } u;
        u.us[0] = f2bf(a.x); u.us[1] = f2bf(a.y); u.us[2] = f2bf(a.z); u.us[3] = f2bf(a.w);
        u.us[4] = f2bf(c.x); u.us[5] = f2bf(c.y); u.us[6] = f2bf(c.z); u.us[7] = f2bf(c.w);
        *(uint4*)(xb + i) = u.v;
        return;
    }
    // ---- conv_w part: 1024 blocks, 4 rows each ----
    const int nb = (bid - CONVX_BLOCKS) * 4;
    const int k0 = threadIdx.x * 8;       // 512 thr * 8 = 4096

    float acc[4][8];
#pragma unroll
    for (int r = 0; r < 4; ++r) {
        const float4* w4 = (const float4*)(W + (size_t)(nb + r) * K_DIM + k0);
        float4 v0 = w4[0], v1 = w4[1];
        acc[r][0] = v0.x; acc[r][1] = v0.y; acc[r][2] = v0.z; acc[r][3] = v0.w;
        acc[r][4] = v1.x; acc[r][5] = v1.y; acc[r][6] = v1.z; acc[r][7] = v1.w;
    }
    float brs[4][16];
#pragma unroll
    for (int r = 0; r < 4; ++r)
#pragma unroll
        for (int t = 0; t < 16; ++t) brs[r][t] = lB[(size_t)(nb + r) * 16 + t];

#pragma unroll
    for (int t = 0; t < 16; ++t) {
        const float4* a4 = (const float4*)(lA + (size_t)t * K_DIM + k0);
        float4 v0 = a4[0], v1 = a4[1];
        float av[8] = {v0.x, v0.y, v0.z, v0.w, v1.x, v1.y, v1.z, v1.w};
#pragma unroll
        for (int r = 0; r < 4; ++r)
#pragma unroll
            for (int j = 0; j < 8; ++j) acc[r][j] += brs[r][t] * av[j];
    }
#pragma unroll
    for (int r = 0; r < 4; ++r) {
        union { unsigned short us[8]; uint4 v; } u;
#pragma unroll
        for (int j = 0; j < 8; ++j) u.us[j] = f2bf(acc[r][j]);
        *(uint4*)(Wb + (size_t)(nb + r) * K_DIM + k0) = u.v;
    }
}

// --- gemm: 256x256 tile, BK=64, 8 waves, m201 8-phase staggered staging -----
// (R13 champion, byte-identical)
__global__ __launch_bounds__(512, 2) void gemm_kernel(
    const unsigned short* __restrict__ A,   // [8192][4096] bf16
    const unsigned short* __restrict__ B,   // [4096][4096] bf16 (W')
    const float* __restrict__ bvec, const float* __restrict__ lbvec,
    float* __restrict__ C) {
    const int tid = threadIdx.x;
    const int lane = tid & 63;
    const int wid = tid >> 6;        // 0..7
    const int wr = wid >> 2;         // 0..1  M-half (128 rows)
    const int wc = wid & 3;          // 0..3  N-quarter (64 cols)

    // XCD-column-resident mapping (R7)
    const int bid = blockIdx.x;
    const int ntile = (bid & 7) * 2 + ((bid >> 3) & 1);  // 0..15
    const int mtile = bid >> 4;                          // 0..31
    const int m0 = mtile * 256, n0 = ntile * 256;

    __shared__ __align__(16) unsigned short ldsA[2 * 2 * 128 * 64];  // 64 KiB
    __shared__ __align__(16) unsigned short ldsB[2 * 2 * 128 * 64];  // 64 KiB

    // --- staging: linear LDS dest, inverse-swizzled global src (T2) ---
    const int lr8 = lane >> 3;             // 0..7
    const int cch = (lane & 7) ^ lr8;      // swizzled 16B-chunk index
    const unsigned short* aSb = A + (size_t)(m0 + lr8) * K_DIM + cch * 8;
    const unsigned short* bSb = B + (size_t)(n0 + lr8) * K_DIM + cch * 8;

    auto stageA = [&](int par_, int h, int kt) {   // one half-tile = 2 loads
#pragma unroll
        for (int s = 0; s < 2; ++s) {
            const int j = wid * 2 + s;
            const unsigned short* g = aSb + (size_t)(h * 128 + j * 8) * K_DIM + kt * 64;
            __builtin_amdgcn_global_load_lds(
                (const __attribute__((address_space(1))) void*)g,
                (__attribute__((address_space(3))) void*)(ldsA + (par_ * 2 + h) * 8192 + j * 512),
                16, 0, 0);
        }
    };
    auto stageB = [&](int par_, int h, int kt) {
#pragma unroll
        for (int s = 0; s < 2; ++s) {
            const int j = wid * 2 + s;
            const unsigned short* g = bSb + (size_t)(h * 128 + j * 8) * K_DIM + kt * 64;
            __builtin_amdgcn_global_load_lds(
                (const __attribute__((address_space(1))) void*)g,
                (__attribute__((address_space(3))) void*)(ldsB + (par_ * 2 + h) * 8192 + j * 512),
                16, 0, 0);
        }
    };

    // --- read side (T2 swizzle) ---
    const int rowByte = (lane & 15) * 128;
    const int swz = (lane & 7) << 4;
    const int kc0 = (0 * 64 + (lane >> 4) * 16) ^ swz;
    const int kc1 = (1 * 64 + (lane >> 4) * 16) ^ swz;
    const int baseBoff = (wc & 1) * 4096;

    auto readA = [&](int par_, int mf, int kk) -> bf16x8 {
        const char* p = (const char*)(ldsA + (par_ * 2 + wr) * 8192 + mf * 1024) +
                        rowByte + (kk ? kc1 : kc0);
        return *(const bf16x8*)p;
    };
    auto readB = [&](int par_, int nf, int kk) -> bf16x8 {
        const char* p = (const char*)(ldsB + (par_ * 2 + (wc >> 1)) * 8192 + baseBoff + nf * 1024) +
                        rowByte + (kk ? kc1 : kc0);
        return *(const bf16x8*)p;
    };

    f32x4 acc[8][4] = {};
    bf16x8 a[4][2], b[4][2];

    auto mfmaQ = [&](int qm, int qn) {   // 16 MFMA: 4 mf x 2 nf x 2 kk
#pragma unroll
        for (int i = 0; i < 4; ++i)
#pragma unroll
            for (int jn = 0; jn < 2; ++jn)
#pragma unroll
                for (int kk = 0; kk < 2; ++kk)
                    acc[qm * 4 + i][qn * 2 + jn] = __builtin_amdgcn_mfma_f32_16x16x32_bf16(
                        a[i][kk], b[qn * 2 + jn][kk], acc[qm * 4 + i][qn * 2 + jn], 0, 0, 0);
    };

    // --- prologue: issue in ledger order A(0),B(0),A(1),B(1); drain t0 ---
    stageA(0, 0, 0); stageA(0, 1, 0); stageB(0, 0, 0); stageB(0, 1, 0);
    stageA(1, 0, 1); stageA(1, 1, 1); stageB(1, 0, 1); stageB(1, 1, 1);
    WAITV8();               // t0's 8 drained; t1's 8 in flight
    BARRIER();              // publish t0

    // Per K-tile: p1: 12 reads + stageA(t+1,h0)   p2: 4 reads + stageA(t+1,h1)
    //             p3: 8 reads + stageB(t+2,h0)    p4: stageB(t+2,h1) + vmcnt(4)
#define KTILE(kt, par)                                                          \
    {                                                                           \
        /* p1 */                                                                \
        _Pragma("unroll") for (int i = 0; i < 4; ++i)                           \
            _Pragma("unroll") for (int kk = 0; kk < 2; ++kk)                    \
                a[i][kk] = readA(par, i, kk);                                    \
        _Pragma("unroll") for (int nf = 0; nf < 2; ++nf)                        \
            _Pragma("unroll") for (int kk = 0; kk < 2; ++kk)                    \
                b[nf][kk] = readB(par, nf, kk);                                  \
        if ((kt) >= 1 && (kt) + 1 < NT) stageA((par) ^ 1, 0, (kt) + 1);         \
        LGKM8();                                                                \
        BARRIER();                                                              \
        LGKM0();                                                                \
        __builtin_amdgcn_s_setprio(1); mfmaQ(0, 0); __builtin_amdgcn_s_setprio(0); \
        BARRIER();                                                              \
        /* p2 */                                                                \
        _Pragma("unroll") for (int nf = 2; nf < 4; ++nf)                        \
            _Pragma("unroll") for (int kk = 0; kk < 2; ++kk)                    \
                b[nf][kk] = readB(par, nf, kk);                                  \
        if ((kt) >= 1 && (kt) + 1 < NT) stageA((par) ^ 1, 1, (kt) + 1);         \
        BARRIER();                                                              \
        LGKM0();                                                                \
        __builtin_amdgcn_s_setprio(1); mfmaQ(0, 1); __builtin_amdgcn_s_setprio(0); \
        BARRIER();                                                              \
        /* p3 (B(par) last read at p2 -> safe to overwrite for t+2) */          \
        _Pragma("unroll") for (int i = 0; i < 4; ++i)                           \
            _Pragma("unroll") for (int kk = 0; kk < 2; ++kk)                    \
                a[i][kk] = readA(par, 4 + i, kk);                                \
        if ((kt) + 2 < NT) stageB(par, 0, (kt) + 2);                            \
        BARRIER();                                                              \
        LGKM0();                                                                \
        __builtin_amdgcn_s_setprio(1); mfmaQ(1, 0); __builtin_amdgcn_s_setprio(0); \
        BARRIER();                                                              \
        /* p4: ledger = 12 outstanding; vmcnt(4) drains {A(t+1),B(t+1)} */      \
        if ((kt) + 2 < NT) { stageB(par, 1, (kt) + 2); WAITV4(); }              \
        else { WAITV0(); }                                                      \
        BARRIER();                                                              \
        __builtin_amdgcn_s_setprio(1); mfmaQ(1, 1); __builtin_amdgcn_s_setprio(0); \
        BARRIER();                                                              \
    }

#pragma unroll 1
    for (int kt = 0; kt < NT; kt += 2) {
        KTILE(kt, 0);
        KTILE(kt + 1, 1);
    }
#undef KTILE

    // --- epilogue: C = acc + (b + lora_bias); NT stores ---
#pragma unroll
    for (int nf = 0; nf < 4; ++nf) {
        const int gc = n0 + wc * 64 + nf * 16 + (lane & 15);
        const float bv = bvec[gc] + lbvec[gc];
#pragma unroll
        for (int mf = 0; mf < 8; ++mf) {
            const int gr0 = m0 + wr * 128 + mf * 16 + (lane >> 4) * 4;
            f32x4 v = acc[mf][nf];
#pragma unroll
            for (int j = 0; j < 4; ++j)
                __builtin_nontemporal_store(v[j] + bv, &C[(size_t)(gr0 + j) * N_DIM + gc]);
        }
    }
}

// --- Fallback: naive fp32 (only if ws too small) ----------------------------
__global__ __launch_bounds__(256) void naive_kernel(
    const float* __restrict__ x, const float* __restrict__ W,
    const float* __restrict__ b, const float* __restrict__ lA,
    const float* __restrict__ lB, const float* __restrict__ lb,
    float* __restrict__ out) {
    __shared__ float xs[K_DIM];
    __shared__ float ts[16];
    const int m = blockIdx.x;
    const int tid = threadIdx.x;
    for (int k = tid; k < K_DIM; k += 256) xs[k] = x[(size_t)m * K_DIM + k];
    if (tid < 16) ts[tid] = 0.f;
    __syncthreads();
    float part[16] = {};
    for (int k = tid * 16; k < tid * 16 + 16; ++k) {
        float xv = xs[k];
#pragma unroll
        for (int r = 0; r < 16; ++r) part[r] += xv * lA[(size_t)r * K_DIM + k];
    }
#pragma unroll
    for (int r = 0; r < 16; ++r) atomicAdd(&ts[r], part[r]);
    __syncthreads();
    const int n = blockIdx.y * 256 + tid;
    float acc = b[n] + lb[n];
#pragma unroll
    for (int r = 0; r < 16; ++r) acc += ts[r] * lB[(size_t)n * 16 + r];
    const float* wrow = W + (size_t)n * K_DIM;
    for (int k = 0; k < K_DIM; ++k) acc += xs[k] * wrow[k];
    out[(size_t)m * N_DIM + n] = acc;
}

// ---------------------------------------------------------------------------
extern "C" void kernel_launch(void* const* d_in, const int* in_sizes, int n_in,
                              void* d_out, int out_size, void* d_ws, size_t ws_size,
                              hipStream_t stream) {
    const float* x  = (const float*)d_in[0];
    const float* W  = (const float*)d_in[1];
    const float* b  = (const float*)d_in[2];
    const float* lA = (const float*)d_in[3];
    const float* lB = (const float*)d_in[4];
    const float* lb = (const float*)d_in[5];
    float* out = (float*)d_out;

    const size_t xb_bytes = (size_t)M_DIM * K_DIM * 2;  // 64 MiB
    const size_t wb_bytes = (size_t)N_DIM * K_DIM * 2;  // 32 MiB

    if (ws_size >= xb_bytes + wb_bytes) {
        unsigned short* xb = (unsigned short*)d_ws;
        unsigned short* wb = (unsigned short*)((char*)d_ws + xb_bytes);

        conv_xw_kernel<<<CONVX_BLOCKS + N_DIM / 4, 512, 0, stream>>>(
            x, xb, W, lA, lB, wb);

        gemm_kernel<<<(M_DIM / 256) * (N_DIM / 256), 512, 0, stream>>>(xb, wb, b, lb, out);
    } else {
        dim3 grid(M_DIM, N_DIM / 256);
        naive_kernel<<<grid, 256, 0, stream>>>(x, W, b, lA, lB, lb, out);
    }
}